// Round 5
// baseline (581.118 us; speedup 1.0000x reference)
//
#include <hip/hip_runtime.h>
#include <stdint.h>

#define N_TOK   4096
#define D_MOD   768
#define D_SPA   24576
#define TOPK    32
#define CAND_CAP 256
#define BAND_CAP 64

typedef __bf16 bf16x8 __attribute__((ext_vector_type(8)));
typedef float  f32x4  __attribute__((ext_vector_type(4)));

__device__ __forceinline__ unsigned short f2bf(float f) {
  uint32_t u = __builtin_bit_cast(uint32_t, f);
  u += 0x7FFFu + ((u >> 16) & 1u);
  return (unsigned short)(u >> 16);
}

__device__ __forceinline__ void glds16(const void* g, void* l) {
  __builtin_amdgcn_global_load_lds(
      (const __attribute__((address_space(1))) unsigned int*)g,
      (__attribute__((address_space(3))) unsigned int*)l,
      16, 0, 0);
}

// ---- K1: fused preprocessing (one dispatch, three roles by block range) ----
__global__ __launch_bounds__(256) void prep(const float* __restrict__ x,
                                            const float* __restrict__ dec_bias,
                                            const float4* __restrict__ Wenc4,
                                            const float* __restrict__ Wd,
                                            unsigned short* __restrict__ xb,
                                            float* __restrict__ tau,
                                            int* __restrict__ cand_cnt,
                                            ushort4* __restrict__ wb4,
                                            float* __restrict__ WdT) {
  __shared__ float tile[32][33];
  __shared__ float s4[4];
  int bid = blockIdx.x;
  int t = threadIdx.x;

  if (bid < 4096) {                       // conv_x + tau
    int row = bid;
    float ss = 0.f;
#pragma unroll
    for (int j = 0; j < 3; ++j) {
      int d = t + j * 256;
      float v = x[(size_t)row * D_MOD + d] - dec_bias[d];
      xb[(size_t)row * D_MOD + d] = f2bf(v);
      ss += v * v;
    }
#pragma unroll
    for (int o = 32; o; o >>= 1) ss += __shfl_xor(ss, o);
    if ((t & 63) == 0) s4[t >> 6] = ss;
    __syncthreads();
    if (t == 0) {
      float tot = s4[0] + s4[1] + s4[2] + s4[3];
      tau[row] = 2.65f * 0.02f * sqrtf(tot);
      cand_cnt[row] = 0;
    }
  } else if (bid < 22528) {               // transpose W_dec
    int id = bid - 4096;
    int tx = t & 31, ty = t >> 5;
    int s0 = (id % 768) * 32;
    int d0 = (id / 768) * 32;
#pragma unroll
    for (int j = 0; j < 4; ++j) {
      int d = d0 + ty + j * 8;
      tile[ty + j * 8][tx] = Wd[(size_t)d * D_SPA + s0 + tx];
    }
    __syncthreads();
#pragma unroll
    for (int j = 0; j < 4; ++j) {
      int s = s0 + ty + j * 8;
      WdT[(size_t)s * D_MOD + d0 + tx] = tile[tx][ty + j * 8];
    }
  } else {                                // conv_we
    const int total4 = D_SPA * D_MOD / 4;
    for (int i = (bid - 22528) * 256 + t; i < total4; i += 4608 * 256) {
      float4 v = Wenc4[i];
      ushort4 o;
      o.x = f2bf(v.x); o.y = f2bf(v.y); o.z = f2bf(v.z); o.w = f2bf(v.w);
      wb4[i] = o;
    }
  }
}

// ---- K2: 256x256 encode GEMM, BK=64, 4 free-running phases, 1 barrier/K-tile ----
// LDS half-tile layout (128 rows x 64 bf16, 16 KB), rotation swizzle:
//   physical 16B-chunk = (logical_chunk + localrow) & 7, rows linear.
// Staged via glds16 (linear dest = thread t covers phys chunk t*16B within
// 8KB j-block); the ROTATION is applied on the global SOURCE address
// (per-lane, allowed) so LDS holds rotated rows. Reads apply same rotation:
//   elem addr = localrow*64 + ((kk*4 + q + r) & 7) * 8   [fm*16 drops: %8==0]
// Bank check: chunk index (q+r+4kk)&7 -> 8 lanes per 4-bank group, full BW.
__global__ __launch_bounds__(512, 2) void gemm_enc(const unsigned short* __restrict__ A,
                                                   const unsigned short* __restrict__ B,
                                                   const float* __restrict__ enc_bias,
                                                   const float* __restrict__ tau,
                                                   int* __restrict__ cand_idx,
                                                   float* __restrict__ cand_val,
                                                   int* __restrict__ cand_cnt) {
  __shared__ unsigned short lds[65536];   // 128 KB: 2 bufs x (A 32KB + B 32KB)
  int id = blockIdx.x;                    // 1536 blocks
  int swz = (id & 7) * 192 + (id >> 3);   // bijective XCD swizzle (1536 = 8*192)
  int tm = swz & 15, tn = swz >> 4;       // 16 x 96 tiles
  int m0 = tm * 256, n0 = tn * 256;
  int t = threadIdx.x;
  int w = t >> 6, l = t & 63;
  int wm = w >> 2, wn = w & 3;            // 2 x 4 wave grid; wave tile 128x64
  int r = l & 15, q = l >> 4;

  f32x4 acc[8][4] = {};

  // staging: thread t covers physical chunk (t&7) of row (t>>3) in j-block
  // source logical chunk cc = (phys_chunk - row) & 7
  const int rowoff = t >> 3;
  const int cc = ((t & 7) - (t >> 3)) & 7;
  const unsigned short* srcA = A + (size_t)(m0 + rowoff) * D_MOD + cc * 8;
  const unsigned short* srcB = B + (size_t)(n0 + rowoff) * D_MOD + cc * 8;
  const int wb = w * 512;                 // wave-uniform LDS elem offset

#define STAGE_A(kt_, b_) do {                                             \
    int kc = (kt_) * 64;                                                  \
    glds16(srcA + kc,            lds + (b_) * 32768 +         wb);        \
    glds16(srcA + kc +  64*768,  lds + (b_) * 32768 +  4096 + wb);        \
    glds16(srcA + kc + 128*768,  lds + (b_) * 32768 +  8192 + wb);        \
    glds16(srcA + kc + 192*768,  lds + (b_) * 32768 + 12288 + wb);        \
  } while (0)
#define STAGE_B(kt_, b_) do {                                             \
    int kc = (kt_) * 64;                                                  \
    glds16(srcB + kc,            lds + (b_) * 32768 + 16384 + wb);        \
    glds16(srcB + kc +  64*768,  lds + (b_) * 32768 + 20480 + wb);        \
    glds16(srcB + kc + 128*768,  lds + (b_) * 32768 + 24576 + wb);        \
    glds16(srcB + kc + 192*768,  lds + (b_) * 32768 + 28672 + wb);        \
  } while (0)

  // read offsets
  const int pc0 = ((q + r) & 7) * 8;      // kk=0
  const int pc1 = pc0 ^ 32;               // kk=1 (chunk ^ 4)
  const int aRow = wm * 8192 + r * 64;                          // + fm*1024
  const int bRow = 16384 + (wn >> 1) * 8192 + ((wn & 1) * 64 + r) * 64; // + fn*1024

  STAGE_A(0, 0);
  STAGE_B(0, 0);
  __syncthreads();                        // drains vmcnt(0): tile 0 resident

  for (int kt = 0; kt < 12; ++kt) {
    const int cur = kt & 1, nxt = cur ^ 1;
    const unsigned short* cp = lds + cur * 32768;
    bf16x8 a0[4][2], a1[4][2], bA[2][2], bB[2][2];

    // ---- phase 0: A-low frags (fm 0-3) | stage A(kt+1) | MFMA q(0,0)
#pragma unroll
    for (int fm = 0; fm < 4; ++fm) {
      a0[fm][0] = *(const bf16x8*)(const void*)(cp + aRow + fm * 1024 + pc0);
      a0[fm][1] = *(const bf16x8*)(const void*)(cp + aRow + fm * 1024 + pc1);
    }
#pragma unroll
    for (int fn = 0; fn < 2; ++fn) {
      bA[fn][0] = *(const bf16x8*)(const void*)(cp + bRow + fn * 1024 + pc0);
      bA[fn][1] = *(const bf16x8*)(const void*)(cp + bRow + fn * 1024 + pc1);
    }
    if (kt < 11) STAGE_A(kt + 1, nxt);
#pragma unroll
    for (int fm = 0; fm < 4; ++fm)
#pragma unroll
      for (int fn = 0; fn < 2; ++fn) {
        acc[fm][fn] = __builtin_amdgcn_mfma_f32_16x16x32_bf16(a0[fm][0], bA[fn][0], acc[fm][fn], 0, 0, 0);
        acc[fm][fn] = __builtin_amdgcn_mfma_f32_16x16x32_bf16(a0[fm][1], bA[fn][1], acc[fm][fn], 0, 0, 0);
      }

    // ---- phase 1: B-high frags (fn 2-3) | stage B(kt+1) | MFMA q(0,1)
#pragma unroll
    for (int fn = 0; fn < 2; ++fn) {
      bB[fn][0] = *(const bf16x8*)(const void*)(cp + bRow + (fn + 2) * 1024 + pc0);
      bB[fn][1] = *(const bf16x8*)(const void*)(cp + bRow + (fn + 2) * 1024 + pc1);
    }
    if (kt < 11) STAGE_B(kt + 1, nxt);
#pragma unroll
    for (int fm = 0; fm < 4; ++fm)
#pragma unroll
      for (int fn = 0; fn < 2; ++fn) {
        acc[fm][fn + 2] = __builtin_amdgcn_mfma_f32_16x16x32_bf16(a0[fm][0], bB[fn][0], acc[fm][fn + 2], 0, 0, 0);
        acc[fm][fn + 2] = __builtin_amdgcn_mfma_f32_16x16x32_bf16(a0[fm][1], bB[fn][1], acc[fm][fn + 2], 0, 0, 0);
      }

    // ---- phase 2: A-high frags (fm 4-7) | MFMA q(1,1)  (reuse bB)
#pragma unroll
    for (int fm = 0; fm < 4; ++fm) {
      a1[fm][0] = *(const bf16x8*)(const void*)(cp + aRow + (fm + 4) * 1024 + pc0);
      a1[fm][1] = *(const bf16x8*)(const void*)(cp + aRow + (fm + 4) * 1024 + pc1);
    }
#pragma unroll
    for (int fm = 0; fm < 4; ++fm)
#pragma unroll
      for (int fn = 0; fn < 2; ++fn) {
        acc[fm + 4][fn + 2] = __builtin_amdgcn_mfma_f32_16x16x32_bf16(a1[fm][0], bB[fn][0], acc[fm + 4][fn + 2], 0, 0, 0);
        acc[fm + 4][fn + 2] = __builtin_amdgcn_mfma_f32_16x16x32_bf16(a1[fm][1], bB[fn][1], acc[fm + 4][fn + 2], 0, 0, 0);
      }

    // ---- phase 3: MFMA q(1,0)  (reuse a1, bA)
#pragma unroll
    for (int fm = 0; fm < 4; ++fm)
#pragma unroll
      for (int fn = 0; fn < 2; ++fn) {
        acc[fm + 4][fn] = __builtin_amdgcn_mfma_f32_16x16x32_bf16(a1[fm][0], bA[fn][0], acc[fm + 4][fn], 0, 0, 0);
        acc[fm + 4][fn] = __builtin_amdgcn_mfma_f32_16x16x32_bf16(a1[fm][1], bA[fn][1], acc[fm + 4][fn], 0, 0, 0);
      }

    // one barrier per K-tile: drains staging (vmcnt 0) + publishes buffers
    __syncthreads();
  }
#undef STAGE_A
#undef STAGE_B

  // ---- fused selection epilogue: append (col, val) where val >= tau[row]
  float bias[4];
#pragma unroll
  for (int fn = 0; fn < 4; ++fn) bias[fn] = enc_bias[n0 + wn * 64 + fn * 16 + r];
#pragma unroll
  for (int fm = 0; fm < 8; ++fm) {
#pragma unroll
    for (int jj = 0; jj < 4; ++jj) {
      int row = m0 + wm * 128 + fm * 16 + q * 4 + jj;
      float trow = tau[row];
#pragma unroll
      for (int fn = 0; fn < 4; ++fn) {
        float v = acc[fm][fn][jj] + bias[fn];
        if (v >= trow) {
          int pos = atomicAdd(&cand_cnt[row], 1);
          if (pos < CAND_CAP) {
            int col = n0 + wn * 64 + fn * 16 + r;
            cand_idx[row * CAND_CAP + pos] = col;
            cand_val[row * CAND_CAP + pos] = v;
          }
        }
      }
    }
  }
}

// ---- K3: fused tail — exact refine + sparse decode + loss partials (per row) ----
__global__ __launch_bounds__(256) void tail_fused(const float* __restrict__ x,
                                                  const float* __restrict__ Wenc,
                                                  const float* __restrict__ enc_bias,
                                                  const float* __restrict__ dec_bias,
                                                  const float* __restrict__ WdT,
                                                  const int* __restrict__ cand_idx,
                                                  const float* __restrict__ cand_val,
                                                  const int* __restrict__ cand_cnt,
                                                  int* __restrict__ top_idx,
                                                  float* __restrict__ top_val,
                                                  float* __restrict__ sae_out,
                                                  double* __restrict__ partials) {
  int row = blockIdx.x;
  int t = threadIdx.x, w = t >> 6, l = t & 63;
  int cnt = cand_cnt[row];
  if (cnt > CAND_CAP) cnt = CAND_CAP;

  __shared__ float xs[D_MOD];
  __shared__ float sVal[CAND_CAP];
  __shared__ int   sIdx[CAND_CAP];
  __shared__ int    rIdx[BAND_CAP];
  __shared__ double rVal[BAND_CAP];
  __shared__ int   rCnt;
  __shared__ float v32sh;
  __shared__ int   tIdxL[TOPK];
  __shared__ float tValL[TOPK];

  for (int i = t; i < D_MOD; i += 256) xs[i] = x[(size_t)row * D_MOD + i] - dec_bias[i];
  if (t < cnt) {
    sIdx[t] = cand_idx[row * CAND_CAP + t];
    sVal[t] = cand_val[row * CAND_CAP + t];
  }
  if (t < TOPK) { tIdxL[t] = 0; tValL[t] = 0.f; }
  if (t == 0) { rCnt = 0; v32sh = -1e30f; }
  __syncthreads();

  float myv = (t < cnt) ? sVal[t] : -1e30f;
  int rank = 0;
  for (int j = 0; j < cnt; ++j) {
    float u = sVal[j];
    rank += (u > myv) || (u == myv && j < t);
  }
  if (t < cnt && rank == 31) v32sh = myv;
  __syncthreads();

  float band = v32sh - 0.02f;
  if (t < cnt && sVal[t] >= band) {
    int p = atomicAdd(&rCnt, 1);
    if (p < BAND_CAP) rIdx[p] = sIdx[t];
  }
  __syncthreads();
  int rn = rCnt > BAND_CAP ? BAND_CAP : rCnt;

  for (int c = w; c < rn; c += 4) {
    int s = rIdx[c];
    const float* wr_ = Wenc + (size_t)s * D_MOD;
    double acc = 0.0;
    for (int i = l; i < D_MOD; i += 64) acc += (double)xs[i] * (double)wr_[i];
#pragma unroll
    for (int o = 32; o; o >>= 1) acc += __shfl_xor(acc, o);
    if (l == 0) {
      double v = acc + (double)enc_bias[s];
      rVal[c] = v > 0.0 ? v : 0.0;
    }
  }
  __syncthreads();

  if (t < rn) {
    double v = rVal[t];
    int myi = rIdx[t];
    int r2 = 0;
    for (int j = 0; j < rn; ++j) {
      double u = rVal[j];
      r2 += (u > v) || (u == v && rIdx[j] < myi);
    }
    if (r2 < TOPK) {
      tIdxL[r2] = myi;
      tValL[r2] = (float)v;
      top_idx[row * TOPK + r2] = myi;
      top_val[row * TOPK + r2] = (float)v;
    }
  }
  __syncthreads();

  float a0 = 0.f, a1 = 0.f, a2 = 0.f;
#pragma unroll 8
  for (int k = 0; k < TOPK; ++k) {
    const float* wc = WdT + (size_t)tIdxL[k] * D_MOD;
    float v = tValL[k];
    a0 += v * wc[t];
    a1 += v * wc[t + 256];
    a2 += v * wc[t + 512];
  }
  float e2 = 0.f;
  {
    sae_out[(size_t)row * D_MOD + t] = a0 + dec_bias[t];
    float e = a0 - xs[t]; e2 += e * e;
  }
  {
    sae_out[(size_t)row * D_MOD + t + 256] = a1 + dec_bias[t + 256];
    float e = a1 - xs[t + 256]; e2 += e * e;
  }
  {
    sae_out[(size_t)row * D_MOD + t + 512] = a2 + dec_bias[t + 512];
    float e = a2 - xs[t + 512]; e2 += e * e;
  }
#pragma unroll
  for (int o = 32; o; o >>= 1) e2 += __shfl_xor(e2, o);
  __shared__ float pw[4];
  if ((t & 63) == 0) pw[t >> 6] = e2;
  __syncthreads();
  if (t == 0) partials[row] = (double)pw[0] + (double)pw[1] + (double)pw[2] + (double)pw[3];
}

// ---- K4: hidden_acts = zeros + scatter ----
__global__ __launch_bounds__(256) void write_hidden(float* __restrict__ hidden,
                                                    const int* __restrict__ top_idx,
                                                    const float* __restrict__ top_val) {
  int row = blockIdx.x;
  int t = threadIdx.x;
  float4* h4 = (float4*)(hidden + (size_t)row * D_SPA);
  float4 z = {0.f, 0.f, 0.f, 0.f};
#pragma unroll
  for (int j = 0; j < 24; ++j) h4[t + j * 256] = z;
  __threadfence_block();
  __syncthreads();
  if (t < TOPK)
    hidden[(size_t)row * D_SPA + top_idx[row * TOPK + t]] = top_val[row * TOPK + t];
}

// ---- K5: final loss reduce ----
__global__ __launch_bounds__(256) void reduce_loss(const double* __restrict__ partials,
                                                   float* __restrict__ scalars) {
  __shared__ double sh[256];
  double s = 0.0;
  for (int i = threadIdx.x; i < N_TOK; i += 256) s += partials[i];
  sh[threadIdx.x] = s;
  __syncthreads();
  for (int o = 128; o; o >>= 1) {
    if (threadIdx.x < o) sh[threadIdx.x] += sh[threadIdx.x + o];
    __syncthreads();
  }
  if (threadIdx.x == 0) {
    double l2 = sh[0];
    scalars[0] = (float)l2;
    scalars[1] = (float)(l2 / ((double)N_TOK * (double)D_MOD));
  }
}

extern "C" void kernel_launch(void* const* d_in, const int* in_sizes, int n_in,
                              void* d_out, int out_size, void* d_ws, size_t ws_size,
                              hipStream_t stream) {
  const float* x        = (const float*)d_in[0];
  const float* Wenc     = (const float*)d_in[1];
  const float* enc_bias = (const float*)d_in[2];
  const float* Wdec     = (const float*)d_in[3];
  const float* dec_bias = (const float*)d_in[4];

  float* out    = (float*)d_out;
  float* sae    = out;
  float* hidden = out + (size_t)N_TOK * D_MOD;
  float* scalars = out + (size_t)N_TOK * D_MOD + (size_t)N_TOK * D_SPA;

  // big scratch inside hidden_acts region (overwritten last by write_hidden)
  char* hbase = (char*)hidden;
  float*          WdT      = (float*)hbase;                         // 75,497,472 B
  unsigned short* WencB    = (unsigned short*)(hbase + 75497472);   // 37,748,736 B
  unsigned short* xB       = (unsigned short*)(hbase + 113246208);  //  6,291,456 B
  int*            cand_idx = (int*)(hbase + 119537664);             //  4,194,304 B
  float*          cand_val = (float*)(hbase + 123731968);           //  4,194,304 B
  int*            cand_cnt = (int*)(hbase + 127926272);             //     16,384 B
  float*          tau      = (float*)(hbase + 127942656);           //     16,384 B

  // small scratch that must survive write_hidden lives in ws
  char* wsb = (char*)d_ws;
  int*    top_idx  = (int*)wsb;
  float*  top_val  = (float*)(wsb + 524288);
  double* partials = (double*)(wsb + 1048576);

  prep<<<27136, 256, 0, stream>>>(x, dec_bias, (const float4*)Wenc, Wdec,
                                  xB, tau, cand_cnt, (ushort4*)WencB, WdT);
  gemm_enc<<<(N_TOK / 256) * (D_SPA / 256), 512, 0, stream>>>(xB, WencB, enc_bias, tau,
                                                              cand_idx, cand_val, cand_cnt);
  tail_fused<<<N_TOK, 256, 0, stream>>>(x, Wenc, enc_bias, dec_bias, WdT,
                                        cand_idx, cand_val, cand_cnt,
                                        top_idx, top_val, sae, partials);
  write_hidden<<<N_TOK, 256, 0, stream>>>(hidden, top_idx, top_val);
  reduce_loss<<<1, 256, 0, stream>>>(partials, scalars);
}